// Round 4
// baseline (324.240 us; speedup 1.0000x reference)
//
#include <hip/hip_runtime.h>
#include <math.h>

#define B_ 4
#define T_ 4096
#define E_ 1024
#define H_ 128
#define S_ 8          // attention split-K factor

typedef __attribute__((ext_vector_type(8))) short short8;
typedef __attribute__((ext_vector_type(4))) float f32x4;
typedef __attribute__((ext_vector_type(16))) float f32x16;
typedef unsigned short ushort;

__device__ __forceinline__ ushort f2bf(float f) {          // RNE
    union { float f; unsigned int u; } v; v.f = f;
    unsigned int r = v.u + 0x7fffu + ((v.u >> 16) & 1u);
    return (ushort)(r >> 16);
}
__device__ __forceinline__ float bf2f(ushort u) {
    union { unsigned int u; float f; } v; v.u = ((unsigned int)u) << 16;
    return v.f;
}
__device__ __forceinline__ unsigned int pkbf(float hi, float lo) { // [bf16(hi)|bf16(lo)] truncated
    return __builtin_amdgcn_perm(__float_as_uint(hi), __float_as_uint(lo), 0x07060302u);
}

typedef __attribute__((address_space(3))) unsigned int lds_u32;
typedef __attribute__((address_space(1))) const unsigned int g_u32;
__device__ __forceinline__ void gload16(const void* g, void* l) {
    __builtin_amdgcn_global_load_lds((g_u32*)g, (lds_u32*)l, 16, 0, 0);
}

// ---------------------------------------------------------------------------
// Kernel 1: W[E][H] fp32 -> Wt[H][E] bf16
// ---------------------------------------------------------------------------
__global__ void prep_w_kernel(const float* __restrict__ Wk,
                              const float* __restrict__ Wq,
                              const float* __restrict__ Wv,
                              ushort* __restrict__ Wt) {
    int sel = blockIdx.y;
    const float* W = (sel == 0) ? Wk : ((sel == 1) ? Wq : Wv);
    ushort* out = Wt + (size_t)sel * (E_ * H_);
    int idx = blockIdx.x * blockDim.x + threadIdx.x;
    if (idx < E_ * H_) {
        int e = idx >> 7;
        int h = idx & (H_ - 1);
        out[(size_t)h * E_ + e] = f2bf(W[idx]);
    }
}

// ---------------------------------------------------------------------------
// Kernel 2: projection GEMM. v5: SINGLE-WAVE blocks, ZERO barriers.
// M-tile 16 (1 wave), BK=32, 32 iters. W staged via global_load_lds into a
// wave-private ring-2 (2 x 8 KB); X dist-1 register prefetch; counted
// s_waitcnt vmcnt(10) orders DMA vs ds_read WITHIN the wave -- no s_barrier
// anywhere in the main loop. ~10 fully independent waves/CU hide latency by
// TLP, which v2-v4 showed the compiler/barriers never deliver within a block.
// ---------------------------------------------------------------------------
__launch_bounds__(64, 4)
__global__ void proj_kernel(const float* __restrict__ Xk,
                            const float* __restrict__ Xq,
                            const float* __restrict__ Xv,
                            const ushort* __restrict__ Wt,
                            ushort* __restrict__ kp,
                            ushort* __restrict__ qp,
                            ushort* __restrict__ vpt) {
    int sel = blockIdx.y;
    const float* X = (sel == 0) ? Xk : ((sel == 1) ? Xq : Xv);
    const ushort* W = Wt + (size_t)sel * (E_ * H_);

    __shared__ __align__(16) ushort smem[8192];    // 16 KB: W ring 2 x 4096
    int lane = threadIdx.x & 63;
    int l15 = lane & 15, quad = lane >> 4;
    int m0 = blockIdx.x * 16;
    int koff = (blockIdx.x & 31) * 32;             // per-block k-stagger

    // stage W tile [128 h][32 k] -> 512 slots of 16B; 8 gload16 per lane.
    // swizzle jst ^ ((row>>1)&3): 16-lane read groups hit 8 distinct
    // bank-quads (2-way aliasing = free, m136).
    auto stageW = [&](int k0, ushort* buf) {
#pragma unroll
        for (int i = 0; i < 8; i++) {
            int slot = i * 64 + lane;
            int row = slot >> 2, jst = slot & 3;
            int jsrc = jst ^ ((row >> 1) & 3);
            gload16(W + (size_t)row * E_ + k0 + jsrc * 8, &buf[slot * 8]);
        }
    };

    const float* xptr = X + (size_t)(m0 + l15) * E_;
    auto loadX = [&](int kk, float4* d) {
        int k0 = (koff + kk * 32) & (E_ - 1);
        d[0] = *(const float4*)(xptr + k0 + quad * 8);
        d[1] = *(const float4*)(xptr + k0 + quad * 8 + 4);
    };

    f32x4 acc[8];
#pragma unroll
    for (int nt = 0; nt < 8; nt++)
#pragma unroll
        for (int j = 0; j < 4; j++) acc[nt][j] = 0.0f;

    float4 xs[2][2];                               // X ring, dist 1

    stageW(koff, smem);
    loadX(0, xs[0]);

#pragma unroll
    for (int kk = 0; kk < 32; kk++) {
        if (kk < 31) {                             // issue tile kk+1 (8+2 VMEM)
            stageW((koff + (kk + 1) * 32) & (E_ - 1), smem + ((kk + 1) & 1) * 4096);
            loadX(kk + 1, xs[(kk + 1) & 1]);
            // newest 10 outstanding = tile kk+1's  =>  tile kk fully landed
            asm volatile("s_waitcnt vmcnt(10)" ::: "memory");
        } else {
            asm volatile("s_waitcnt vmcnt(0)" ::: "memory");
        }
        const float4* x = xs[kk & 1];
        union { unsigned int w[4]; short8 s8; } au;
        au.w[0] = pkbf(x[0].y, x[0].x);  au.w[1] = pkbf(x[0].w, x[0].z);
        au.w[2] = pkbf(x[1].y, x[1].x);  au.w[3] = pkbf(x[1].w, x[1].z);
        const ushort* Wcur = smem + (kk & 1) * 4096;
#pragma unroll
        for (int nt = 0; nt < 8; nt++) {
            int n = nt * 16 + l15;
            int jj = quad ^ ((n >> 1) & 3);
            short8 bb = *(const short8*)&Wcur[n * 32 + jj * 8];
            acc[nt] = __builtin_amdgcn_mfma_f32_16x16x32_bf16(au.s8, bb, acc[nt], 0, 0, 0);
        }
    }

    if (sel < 2) {
        float scale = (sel == 1) ? 0.08838834764831845f : 1.0f;
        ushort* out = (sel == 0) ? kp : qp;
#pragma unroll
        for (int nt = 0; nt < 8; nt++)
#pragma unroll
            for (int r = 0; r < 4; r++) {
                int row = m0 + quad * 4 + r;
                out[(size_t)row * H_ + nt * 16 + l15] = f2bf(acc[nt][r] * scale);
            }
    } else {
        // transpose 16 t-rows x 128 h-cols -> vpt[h][t] via LDS [128 h][24]
        // (single wave: lgkmcnt ordering only, no barrier)
        ushort* Ot = smem;
#pragma unroll
        for (int nt = 0; nt < 8; nt++) {
            unsigned int p0 = ((unsigned int)f2bf(acc[nt][0])) | ((unsigned int)f2bf(acc[nt][1]) << 16);
            unsigned int p1 = ((unsigned int)f2bf(acc[nt][2])) | ((unsigned int)f2bf(acc[nt][3]) << 16);
            *(uint2*)&Ot[(nt * 16 + l15) * 24 + quad * 4] = make_uint2(p0, p1);
        }
        int b = m0 >> 12;
        int t0 = m0 & (T_ - 1);
#pragma unroll
        for (int rr = 0; rr < 2; rr++) {
            int hh = lane * 2 + rr;
            ushort* dst = vpt + (size_t)b * H_ * T_ + (size_t)hh * T_ + t0;
            const ushort* src = &Ot[hh * 24];
            *(uint4*)(dst)     = *(const uint4*)(src);
            *(uint4*)(dst + 8) = *(const uint4*)(src + 8);
        }
    }
}

// ---------------------------------------------------------------------------
// Kernel 3: flash attention partials, 32x32x16 MFMA, split-K S_=8
// Wave = 32 queries; S^T = K Q^T; O^T = V^T P^T (P via shfl_xor(32), no LDS P)
// K/V double-buffered via global_load_lds; heavy (large-qt) blocks launch 1st.
// ---------------------------------------------------------------------------
__launch_bounds__(256, 2)
__global__ void attn_kernel(const ushort* __restrict__ kp,
                            const ushort* __restrict__ qp,
                            const ushort* __restrict__ vpt,
                            ushort* __restrict__ Opart,
                            float* __restrict__ Mpart,
                            float* __restrict__ Lpart) {
    __shared__ __align__(16) ushort smem[32768];   // 64 KB: 2 x (Ks 8192 + Vs 8192)
    int t = threadIdx.x;
    int wave = t >> 6, lane = t & 63;
    int l31 = lane & 31, h = lane >> 5;
    int s = blockIdx.x;
    int qt = (int)gridDim.y - 1 - (int)blockIdx.y;   // heavy blocks first
    int b = blockIdx.z;
    int q0 = qt * 128;
    int nkt = 2 * qt + 2;
    int query = q0 + wave * 32 + l31;

    const ushort* kbase = kp + (size_t)b * T_ * H_;
    const ushort* vbase = vpt + (size_t)b * H_ * T_;

    // Q as B-operand (32x32x16): B[n=query=lane&31][k=h=(lane>>5)*8+j], 8 steps
    short8 qf[8];
#pragma unroll
    for (int kh = 0; kh < 8; kh++)
        qf[kh] = *(const short8*)(qp + ((size_t)b * T_ + query) * H_ + kh * 16 + h * 8);

    f32x16 ao[4];                         // O^T acc: [hc][reg], col = query
#pragma unroll
    for (int hc = 0; hc < 4; hc++)
#pragma unroll
        for (int j = 0; j < 16; j++) ao[hc][j] = 0.0f;
    float m_i = -INFINITY, l_i = 0.0f;

    auto stage = [&](int kt, int buf) {
        ushort* Ksb = smem + buf * 16384;
        ushort* Vsb = Ksb + 8192;
        int k0 = kt * 64;
#pragma unroll
        for (int i = 0; i < 4; i++) {
            int slot = i * 256 + t;
            int row = slot >> 4, jst = slot & 15;
            int jsrc = jst ^ (row & 15);
            gload16(kbase + (size_t)(k0 + row) * H_ + jsrc * 8, &Ksb[slot * 8]);
        }
#pragma unroll
        for (int i = 0; i < 4; i++) {
            int slot = i * 256 + t;
            int row = slot >> 3, jst = slot & 7;
            int jsrc = jst ^ (row & 7);
            gload16(vbase + (size_t)row * T_ + k0 + jsrc * 8, &Vsb[slot * 8]);
        }
    };

    int cur = 0;
    if (s < nkt) stage(s, 0);

    for (int kt = s; kt < nkt; kt += S_) {
        __syncthreads();                   // cur buffers ready
        if (kt + S_ < nkt) stage(kt + S_, cur ^ 1);
        const ushort* Ksb = smem + cur * 16384;
        const ushort* Vsb = Ksb + 8192;
        int k0 = kt * 64;

        // S^T = K Q^T : s0 = keys 0..31, s1 = keys 32..63; col = query
        f32x16 s0, s1;
#pragma unroll
        for (int j = 0; j < 16; j++) { s0[j] = 0.0f; s1[j] = 0.0f; }
#pragma unroll
        for (int kh = 0; kh < 8; kh++) {
            int slot = (kh * 2 + h) ^ (l31 & 15);
            short8 a0 = *(const short8*)&Ksb[l31 * 128 + slot * 8];
            short8 a1 = *(const short8*)&Ksb[(32 + l31) * 128 + slot * 8];
            s0 = __builtin_amdgcn_mfma_f32_32x32x16_bf16(a0, qf[kh], s0, 0, 0, 0);
            s1 = __builtin_amdgcn_mfma_f32_32x32x16_bf16(a1, qf[kh], s1, 0, 0, 0);
        }

        // causal mask: key row = (r&3)+8*(r>>2)+4h (+32 for s1)
        if (k0 + 63 > q0 + wave * 32) {
#pragma unroll
            for (int rq = 0; rq < 4; rq++)
#pragma unroll
                for (int rr = 0; rr < 4; rr++) {
                    int koff = rr + rq * 8 + h * 4;
                    if (k0 + koff > query)      s0[rq * 4 + rr] = -INFINITY;
                    if (k0 + 32 + koff > query) s1[rq * 4 + rr] = -INFINITY;
                }
        }

        // online softmax per query (in-lane over 32 + one shfl_xor(32))
        float cmax = -INFINITY;
#pragma unroll
        for (int j = 0; j < 16; j++) cmax = fmaxf(cmax, fmaxf(s0[j], s1[j]));
        cmax = fmaxf(cmax, __shfl_xor(cmax, 32));
        float mnew = fmaxf(m_i, cmax);
        float msafe = fmaxf(mnew, -1e30f);
        float alpha = __expf(m_i - msafe);
        m_i = mnew;
        float rs = 0.0f;
#pragma unroll
        for (int j = 0; j < 16; j++) {
            s0[j] = __expf(s0[j] - msafe);
            s1[j] = __expf(s1[j] - msafe);
            rs += s0[j] + s1[j];
        }
        rs += __shfl_xor(rs, 32);
        l_i = l_i * alpha + rs;
#pragma unroll
        for (int hc = 0; hc < 4; hc++)
#pragma unroll
            for (int j = 0; j < 16; j++) ao[hc][j] *= alpha;

        // O^T += V^T P^T ; P^T B-frag built via shfl_xor(32) from S^T C-frags
#pragma unroll
        for (int kk = 0; kk < 4; kk++) {
            const f32x16& sf = (kk < 2) ? s0 : s1;
            int base = (kk & 1) * 8;
            unsigned int q0x = pkbf(sf[base + 1], sf[base + 0]);
            unsigned int q0y = pkbf(sf[base + 3], sf[base + 2]);
            unsigned int q1x = pkbf(sf[base + 5], sf[base + 4]);
            unsigned int q1y = pkbf(sf[base + 7], sf[base + 6]);
            unsigned int t0x = __shfl_xor(q0x, 32);
            unsigned int t0y = __shfl_xor(q0y, 32);
            unsigned int t1x = __shfl_xor(q1x, 32);
            unsigned int t1y = __shfl_xor(q1y, 32);
            union { unsigned int w[4]; short8 s8; } bu;
            bu.w[0] = h ? t1x : q0x;
            bu.w[1] = h ? t1y : q0y;
            bu.w[2] = h ? q1x : t0x;
            bu.w[3] = h ? q1y : t0y;
#pragma unroll
            for (int hc = 0; hc < 4; hc++) {
                int row = hc * 32 + l31;
                int slot = (kk * 2 + h) ^ (row & 7);
                short8 av = *(const short8*)&Vsb[row * 64 + slot * 8];
                ao[hc] = __builtin_amdgcn_mfma_f32_32x32x16_bf16(av, bu.s8, ao[hc], 0, 0, 0);
            }
        }
        cur ^= 1;
    }

    // epilogue
    const size_t BT = (size_t)B_ * T_;
    __syncthreads();                       // all compute done before aliasing smem
    if (lane < 32) {
        int grow = b * T_ + query;
        Mpart[(size_t)s * BT + grow] = m_i;
        Lpart[(size_t)s * BT + grow] = l_i;
    }
    ushort* Ot = smem;                     // [128 q][136]
#pragma unroll
    for (int hc = 0; hc < 4; hc++)
#pragma unroll
        for (int rq = 0; rq < 4; rq++) {
            uint2 w = make_uint2(
                ((unsigned int)f2bf(ao[hc][rq * 4 + 0])) | ((unsigned int)f2bf(ao[hc][rq * 4 + 1]) << 16),
                ((unsigned int)f2bf(ao[hc][rq * 4 + 2])) | ((unsigned int)f2bf(ao[hc][rq * 4 + 3]) << 16));
            *(uint2*)&Ot[(wave * 32 + l31) * 136 + hc * 32 + rq * 8 + h * 4] = w;
        }
    __syncthreads();
    {
        int qq = t >> 1, half = (t & 1) * 64;
        size_t row = (size_t)s * BT + b * T_ + q0 + qq;
        ushort* dst = Opart + row * H_ + half;
        const ushort* src = &Ot[qq * 136 + half];
#pragma unroll
        for (int j = 0; j < 8; j++)
            *(uint4*)(dst + j * 8) = *(const uint4*)(src + j * 8);
    }
}

// ---------------------------------------------------------------------------
// Kernel 4: combine split-K partials
// ---------------------------------------------------------------------------
__launch_bounds__(256)
__global__ void combine_kernel(const ushort* __restrict__ Opart,
                               const float* __restrict__ Mpart,
                               const float* __restrict__ Lpart,
                               float* __restrict__ out) {
    int t = threadIdx.x;
    int row = blockIdx.x * 2 + (t >> 7);
    int col = t & 127;
    const size_t BT = (size_t)B_ * T_;
    float m[S_], l[S_];
#pragma unroll
    for (int s = 0; s < S_; s++) {
        m[s] = Mpart[(size_t)s * BT + row];
        l[s] = Lpart[(size_t)s * BT + row];
    }
    float M = m[0];
#pragma unroll
    for (int s = 1; s < S_; s++) M = fmaxf(M, m[s]);
    float den = 0.0f, acc = 0.0f;
#pragma unroll
    for (int s = 0; s < S_; s++) {
        float w = __expf(m[s] - M);
        den += l[s] * w;
        acc += w * bf2f(Opart[((size_t)s * BT + row) * H_ + col]);
    }
    out[(size_t)row * H_ + col] = acc / den;
}

// ---------------------------------------------------------------------------
extern "C" void kernel_launch(void* const* d_in, const int* in_sizes, int n_in,
                              void* d_out, int out_size, void* d_ws, size_t ws_size,
                              hipStream_t stream) {
    (void)in_sizes; (void)n_in; (void)out_size; (void)ws_size;
    const float* k  = (const float*)d_in[0];
    const float* q  = (const float*)d_in[1];
    const float* v  = (const float*)d_in[2];
    const float* Wk = (const float*)d_in[3];
    const float* Wq = (const float*)d_in[4];
    const float* Wv = (const float*)d_in[5];

    ushort* wsu = (ushort*)d_ws;
    const size_t PROJ_ELEMS = (size_t)B_ * T_ * H_;        // 2,097,152
    ushort* kp  = wsu;
    ushort* qp  = wsu + PROJ_ELEMS;
    ushort* vpt = wsu + 2 * PROJ_ELEMS;
    ushort* Wt  = wsu + 3 * PROJ_ELEMS;                    // 393,216 ushorts
    char*  fbase = (char*)d_ws + (3 * PROJ_ELEMS + 393216) * sizeof(ushort);
    float* Mpart = (float*)fbase;                          // S_*B*T floats
    float* Lpart = Mpart + (size_t)S_ * B_ * T_;
    ushort* Opart = (ushort*)(Lpart + (size_t)S_ * B_ * T_);  // S_*B*T*H bf16

    prep_w_kernel<<<dim3((E_ * H_ + 255) / 256, 3), 256, 0, stream>>>(Wk, Wq, Wv, Wt);
    proj_kernel<<<dim3((B_ * T_) / 16, 3), 64, 0, stream>>>(k, q, v, Wt, kp, qp, vpt);
    attn_kernel<<<dim3(S_, T_ / 128, B_), 256, 0, stream>>>(kp, qp, vpt, Opart, Mpart, Lpart);
    combine_kernel<<<dim3(B_ * T_ / 2), 256, 0, stream>>>(Opart, Mpart, Lpart, (float*)d_out);
}

// Round 5
// 278.538 us; speedup vs baseline: 1.1641x; 1.1641x over previous
//
#include <hip/hip_runtime.h>
#include <math.h>

#define B_ 4
#define T_ 4096
#define E_ 1024
#define H_ 128
#define S_ 8          // attention split-K factor

typedef __attribute__((ext_vector_type(8))) short short8;
typedef __attribute__((ext_vector_type(4))) float f32x4;
typedef __attribute__((ext_vector_type(16))) float f32x16;
typedef unsigned short ushort;

__device__ __forceinline__ ushort f2bf(float f) {          // RNE
    union { float f; unsigned int u; } v; v.f = f;
    unsigned int r = v.u + 0x7fffu + ((v.u >> 16) & 1u);
    return (ushort)(r >> 16);
}
__device__ __forceinline__ float bf2f(ushort u) {
    union { unsigned int u; float f; } v; v.u = ((unsigned int)u) << 16;
    return v.f;
}
__device__ __forceinline__ unsigned int pkbf(float hi, float lo) { // [bf16(hi)|bf16(lo)] truncated
    return __builtin_amdgcn_perm(__float_as_uint(hi), __float_as_uint(lo), 0x07060302u);
}

typedef __attribute__((address_space(3))) unsigned int lds_u32;
typedef __attribute__((address_space(1))) const unsigned int g_u32;
__device__ __forceinline__ void gload16(const void* g, void* l) {
    __builtin_amdgcn_global_load_lds((g_u32*)g, (lds_u32*)l, 16, 0, 0);
}

// ---------------------------------------------------------------------------
// Kernel 1: W[E][H] fp32 -> Wt[H][E] bf16
// ---------------------------------------------------------------------------
__global__ void prep_w_kernel(const float* __restrict__ Wk,
                              const float* __restrict__ Wq,
                              const float* __restrict__ Wv,
                              ushort* __restrict__ Wt) {
    int sel = blockIdx.y;
    const float* W = (sel == 0) ? Wk : ((sel == 1) ? Wq : Wv);
    ushort* out = Wt + (size_t)sel * (E_ * H_);
    int idx = blockIdx.x * blockDim.x + threadIdx.x;
    if (idx < E_ * H_) {
        int e = idx >> 7;
        int h = idx & (H_ - 1);
        out[(size_t)h * E_ + e] = f2bf(W[idx]);
    }
}

// ---------------------------------------------------------------------------
// Kernel 2: projection GEMM. v6 = v1's exact schedule (dbuf LDS W, one
// __syncthreads per K-step, prefetch dist 1), but M-tile 32 / 128-thread
// 2-wave blocks / grid 1536: 5 LDS-resident blocks per CU (v1 was grid-capped
// at 3, measured ~2.5). Evidence r0-r4: proj time tracks independent resident
// streams/CU and responds to nothing else; per-wave work here is IDENTICAL to
// v1, only convoy width (2 waves) and convoys/CU (5) change.
// ---------------------------------------------------------------------------
__launch_bounds__(128, 3)
__global__ void proj_kernel(const float* __restrict__ Xk,
                            const float* __restrict__ Xq,
                            const float* __restrict__ Xv,
                            const ushort* __restrict__ Wt,
                            ushort* __restrict__ kp,
                            ushort* __restrict__ qp,
                            ushort* __restrict__ vpt) {
    int sel = blockIdx.y;
    const float* X = (sel == 0) ? Xk : ((sel == 1) ? Xq : Xv);
    const ushort* W = Wt + (size_t)sel * (E_ * H_);

    __shared__ __align__(16) ushort smem[16384];   // 32 KB: Ws dbuf 2 x 8192
    ushort* Ot = smem;                             // epilogue alias [128 h][40]

    int t = threadIdx.x;
    int wave = t >> 6, lane = t & 63;
    int l15 = lane & 15, quad = lane >> 4;
    int m0 = blockIdx.x * 32;
    int koff = (blockIdx.x & 15) * 64;             // per-block k-stagger

    auto stageW = [&](int k0, ushort* buf) {
#pragma unroll
        for (int i = 0; i < 8; i++) {
            int slot = i * 128 + t;
            int row = slot >> 3, jst = slot & 7;
            int jsrc = jst ^ (row & 7);
            gload16(W + (size_t)row * E_ + k0 + jsrc * 8, &buf[slot * 8]);
        }
    };

    const float* xptr = X + (size_t)(m0 + wave * 16 + l15) * E_;
    float4 xa, xb, xc, xd;
    auto loadX = [&](int k0, float4& a, float4& b, float4& c, float4& d) {
        a = *(const float4*)(xptr + k0 + quad * 8);
        b = *(const float4*)(xptr + k0 + quad * 8 + 4);
        c = *(const float4*)(xptr + k0 + 32 + quad * 8);
        d = *(const float4*)(xptr + k0 + 32 + quad * 8 + 4);
    };

    f32x4 acc[8];
#pragma unroll
    for (int nt = 0; nt < 8; nt++)
#pragma unroll
        for (int j = 0; j < 4; j++) acc[nt][j] = 0.0f;

    stageW(koff, smem);
    loadX(koff, xa, xb, xc, xd);

    for (int it = 0; it < 16; it++) {
        __syncthreads();                   // cur buf ready (staged last iter)
        ushort* Wcur = (it & 1) ? (smem + 8192) : smem;
        ushort* Walt = (it & 1) ? smem : (smem + 8192);
        bool more = (it + 1 < 16);
        int knext = (koff + (it + 1) * 64) & (E_ - 1);
        float4 na, nb, nc, nd;
        if (more) {
            stageW(knext, Walt);           // in flight during compute below
            loadX(knext, na, nb, nc, nd);
        }
#pragma unroll
        for (int ks = 0; ks < 2; ks++) {
            const float4& u  = ks ? xc : xa;
            const float4& v2 = ks ? xd : xb;
            union { unsigned int w[4]; short8 s8; } au;
            au.w[0] = pkbf(u.y, u.x);  au.w[1] = pkbf(u.w, u.z);
            au.w[2] = pkbf(v2.y, v2.x); au.w[3] = pkbf(v2.w, v2.z);
#pragma unroll
            for (int nt = 0; nt < 8; nt++) {
                int n = nt * 16 + l15;
                int jj = (ks * 4 + quad) ^ (n & 7);
                short8 b = *(const short8*)&Wcur[n * 64 + jj * 8];
                acc[nt] = __builtin_amdgcn_mfma_f32_16x16x32_bf16(au.s8, b, acc[nt], 0, 0, 0);
            }
        }
        if (more) { xa = na; xb = nb; xc = nc; xd = nd; }
    }

    if (sel < 2) {
        float scale = (sel == 1) ? 0.08838834764831845f : 1.0f;
        ushort* out = (sel == 0) ? kp : qp;
#pragma unroll
        for (int nt = 0; nt < 8; nt++)
#pragma unroll
            for (int r = 0; r < 4; r++) {
                int row = m0 + wave * 16 + quad * 4 + r;
                out[(size_t)row * H_ + nt * 16 + l15] = f2bf(acc[nt][r] * scale);
            }
    } else {
        __syncthreads();                   // done with Ws before aliasing
#pragma unroll
        for (int nt = 0; nt < 8; nt++) {
            unsigned int p0 = ((unsigned int)f2bf(acc[nt][0])) | ((unsigned int)f2bf(acc[nt][1]) << 16);
            unsigned int p1 = ((unsigned int)f2bf(acc[nt][2])) | ((unsigned int)f2bf(acc[nt][3]) << 16);
            *(uint2*)&Ot[(nt * 16 + l15) * 40 + wave * 16 + quad * 4] = make_uint2(p0, p1);
        }
        __syncthreads();
        int b = m0 >> 12;
        int t0 = m0 & (T_ - 1);
        int h = t;                          // 128 threads = 128 h-rows
        ushort* dst = vpt + (size_t)b * H_ * T_ + (size_t)h * T_ + t0;
        const ushort* src = &Ot[h * 40];
#pragma unroll
        for (int j = 0; j < 4; j++)
            *(uint4*)(dst + j * 8) = *(const uint4*)(src + j * 8);
    }
}

// ---------------------------------------------------------------------------
// Kernel 3: flash attention partials, 32x32x16 MFMA, split-K S_=8
// Wave = 32 queries; S^T = K Q^T; O^T = V^T P^T (P via shfl_xor(32), no LDS P)
// K/V double-buffered via global_load_lds; heavy (large-qt) blocks launch 1st.
// ---------------------------------------------------------------------------
__launch_bounds__(256, 2)
__global__ void attn_kernel(const ushort* __restrict__ kp,
                            const ushort* __restrict__ qp,
                            const ushort* __restrict__ vpt,
                            ushort* __restrict__ Opart,
                            float* __restrict__ Mpart,
                            float* __restrict__ Lpart) {
    __shared__ __align__(16) ushort smem[32768];   // 64 KB: 2 x (Ks 8192 + Vs 8192)
    int t = threadIdx.x;
    int wave = t >> 6, lane = t & 63;
    int l31 = lane & 31, h = lane >> 5;
    int s = blockIdx.x;
    int qt = (int)gridDim.y - 1 - (int)blockIdx.y;   // heavy blocks first
    int b = blockIdx.z;
    int q0 = qt * 128;
    int nkt = 2 * qt + 2;
    int query = q0 + wave * 32 + l31;

    const ushort* kbase = kp + (size_t)b * T_ * H_;
    const ushort* vbase = vpt + (size_t)b * H_ * T_;

    // Q as B-operand (32x32x16): B[n=query=lane&31][k=h=(lane>>5)*8+j], 8 steps
    short8 qf[8];
#pragma unroll
    for (int kh = 0; kh < 8; kh++)
        qf[kh] = *(const short8*)(qp + ((size_t)b * T_ + query) * H_ + kh * 16 + h * 8);

    f32x16 ao[4];                         // O^T acc: [hc][reg], col = query
#pragma unroll
    for (int hc = 0; hc < 4; hc++)
#pragma unroll
        for (int j = 0; j < 16; j++) ao[hc][j] = 0.0f;
    float m_i = -INFINITY, l_i = 0.0f;

    auto stage = [&](int kt, int buf) {
        ushort* Ksb = smem + buf * 16384;
        ushort* Vsb = Ksb + 8192;
        int k0 = kt * 64;
#pragma unroll
        for (int i = 0; i < 4; i++) {
            int slot = i * 256 + t;
            int row = slot >> 4, jst = slot & 15;
            int jsrc = jst ^ (row & 15);
            gload16(kbase + (size_t)(k0 + row) * H_ + jsrc * 8, &Ksb[slot * 8]);
        }
#pragma unroll
        for (int i = 0; i < 4; i++) {
            int slot = i * 256 + t;
            int row = slot >> 3, jst = slot & 7;
            int jsrc = jst ^ (row & 7);
            gload16(vbase + (size_t)row * T_ + k0 + jsrc * 8, &Vsb[slot * 8]);
        }
    };

    int cur = 0;
    if (s < nkt) stage(s, 0);

    for (int kt = s; kt < nkt; kt += S_) {
        __syncthreads();                   // cur buffers ready
        if (kt + S_ < nkt) stage(kt + S_, cur ^ 1);
        const ushort* Ksb = smem + cur * 16384;
        const ushort* Vsb = Ksb + 8192;
        int k0 = kt * 64;

        // S^T = K Q^T : s0 = keys 0..31, s1 = keys 32..63; col = query
        f32x16 s0, s1;
#pragma unroll
        for (int j = 0; j < 16; j++) { s0[j] = 0.0f; s1[j] = 0.0f; }
#pragma unroll
        for (int kh = 0; kh < 8; kh++) {
            int slot = (kh * 2 + h) ^ (l31 & 15);
            short8 a0 = *(const short8*)&Ksb[l31 * 128 + slot * 8];
            short8 a1 = *(const short8*)&Ksb[(32 + l31) * 128 + slot * 8];
            s0 = __builtin_amdgcn_mfma_f32_32x32x16_bf16(a0, qf[kh], s0, 0, 0, 0);
            s1 = __builtin_amdgcn_mfma_f32_32x32x16_bf16(a1, qf[kh], s1, 0, 0, 0);
        }

        // causal mask: key row = (r&3)+8*(r>>2)+4h (+32 for s1)
        if (k0 + 63 > q0 + wave * 32) {
#pragma unroll
            for (int rq = 0; rq < 4; rq++)
#pragma unroll
                for (int rr = 0; rr < 4; rr++) {
                    int koff = rr + rq * 8 + h * 4;
                    if (k0 + koff > query)      s0[rq * 4 + rr] = -INFINITY;
                    if (k0 + 32 + koff > query) s1[rq * 4 + rr] = -INFINITY;
                }
        }

        // online softmax per query (in-lane over 32 + one shfl_xor(32))
        float cmax = -INFINITY;
#pragma unroll
        for (int j = 0; j < 16; j++) cmax = fmaxf(cmax, fmaxf(s0[j], s1[j]));
        cmax = fmaxf(cmax, __shfl_xor(cmax, 32));
        float mnew = fmaxf(m_i, cmax);
        float msafe = fmaxf(mnew, -1e30f);
        float alpha = __expf(m_i - msafe);
        m_i = mnew;
        float rs = 0.0f;
#pragma unroll
        for (int j = 0; j < 16; j++) {
            s0[j] = __expf(s0[j] - msafe);
            s1[j] = __expf(s1[j] - msafe);
            rs += s0[j] + s1[j];
        }
        rs += __shfl_xor(rs, 32);
        l_i = l_i * alpha + rs;
#pragma unroll
        for (int hc = 0; hc < 4; hc++)
#pragma unroll
            for (int j = 0; j < 16; j++) ao[hc][j] *= alpha;

        // O^T += V^T P^T ; P^T B-frag built via shfl_xor(32) from S^T C-frags
#pragma unroll
        for (int kk = 0; kk < 4; kk++) {
            const f32x16& sf = (kk < 2) ? s0 : s1;
            int base = (kk & 1) * 8;
            unsigned int q0x = pkbf(sf[base + 1], sf[base + 0]);
            unsigned int q0y = pkbf(sf[base + 3], sf[base + 2]);
            unsigned int q1x = pkbf(sf[base + 5], sf[base + 4]);
            unsigned int q1y = pkbf(sf[base + 7], sf[base + 6]);
            unsigned int t0x = __shfl_xor(q0x, 32);
            unsigned int t0y = __shfl_xor(q0y, 32);
            unsigned int t1x = __shfl_xor(q1x, 32);
            unsigned int t1y = __shfl_xor(q1y, 32);
            union { unsigned int w[4]; short8 s8; } bu;
            bu.w[0] = h ? t1x : q0x;
            bu.w[1] = h ? t1y : q0y;
            bu.w[2] = h ? q1x : t0x;
            bu.w[3] = h ? q1y : t0y;
#pragma unroll
            for (int hc = 0; hc < 4; hc++) {
                int row = hc * 32 + l31;
                int slot = (kk * 2 + h) ^ (row & 7);
                short8 av = *(const short8*)&Vsb[row * 64 + slot * 8];
                ao[hc] = __builtin_amdgcn_mfma_f32_32x32x16_bf16(av, bu.s8, ao[hc], 0, 0, 0);
            }
        }
        cur ^= 1;
    }

    // epilogue
    const size_t BT = (size_t)B_ * T_;
    __syncthreads();                       // all compute done before aliasing smem
    if (lane < 32) {
        int grow = b * T_ + query;
        Mpart[(size_t)s * BT + grow] = m_i;
        Lpart[(size_t)s * BT + grow] = l_i;
    }
    ushort* Ot = smem;                     // [128 q][136]
#pragma unroll
    for (int hc = 0; hc < 4; hc++)
#pragma unroll
        for (int rq = 0; rq < 4; rq++) {
            uint2 w = make_uint2(
                ((unsigned int)f2bf(ao[hc][rq * 4 + 0])) | ((unsigned int)f2bf(ao[hc][rq * 4 + 1]) << 16),
                ((unsigned int)f2bf(ao[hc][rq * 4 + 2])) | ((unsigned int)f2bf(ao[hc][rq * 4 + 3]) << 16));
            *(uint2*)&Ot[(wave * 32 + l31) * 136 + hc * 32 + rq * 8 + h * 4] = w;
        }
    __syncthreads();
    {
        int qq = t >> 1, half = (t & 1) * 64;
        size_t row = (size_t)s * BT + b * T_ + q0 + qq;
        ushort* dst = Opart + row * H_ + half;
        const ushort* src = &Ot[qq * 136 + half];
#pragma unroll
        for (int j = 0; j < 8; j++)
            *(uint4*)(dst + j * 8) = *(const uint4*)(src + j * 8);
    }
}

// ---------------------------------------------------------------------------
// Kernel 4: combine split-K partials
// ---------------------------------------------------------------------------
__launch_bounds__(256)
__global__ void combine_kernel(const ushort* __restrict__ Opart,
                               const float* __restrict__ Mpart,
                               const float* __restrict__ Lpart,
                               float* __restrict__ out) {
    int t = threadIdx.x;
    int row = blockIdx.x * 2 + (t >> 7);
    int col = t & 127;
    const size_t BT = (size_t)B_ * T_;
    float m[S_], l[S_];
#pragma unroll
    for (int s = 0; s < S_; s++) {
        m[s] = Mpart[(size_t)s * BT + row];
        l[s] = Lpart[(size_t)s * BT + row];
    }
    float M = m[0];
#pragma unroll
    for (int s = 1; s < S_; s++) M = fmaxf(M, m[s]);
    float den = 0.0f, acc = 0.0f;
#pragma unroll
    for (int s = 0; s < S_; s++) {
        float w = __expf(m[s] - M);
        den += l[s] * w;
        acc += w * bf2f(Opart[((size_t)s * BT + row) * H_ + col]);
    }
    out[(size_t)row * H_ + col] = acc / den;
}

// ---------------------------------------------------------------------------
extern "C" void kernel_launch(void* const* d_in, const int* in_sizes, int n_in,
                              void* d_out, int out_size, void* d_ws, size_t ws_size,
                              hipStream_t stream) {
    (void)in_sizes; (void)n_in; (void)out_size; (void)ws_size;
    const float* k  = (const float*)d_in[0];
    const float* q  = (const float*)d_in[1];
    const float* v  = (const float*)d_in[2];
    const float* Wk = (const float*)d_in[3];
    const float* Wq = (const float*)d_in[4];
    const float* Wv = (const float*)d_in[5];

    ushort* wsu = (ushort*)d_ws;
    const size_t PROJ_ELEMS = (size_t)B_ * T_ * H_;        // 2,097,152
    ushort* kp  = wsu;
    ushort* qp  = wsu + PROJ_ELEMS;
    ushort* vpt = wsu + 2 * PROJ_ELEMS;
    ushort* Wt  = wsu + 3 * PROJ_ELEMS;                    // 393,216 ushorts
    char*  fbase = (char*)d_ws + (3 * PROJ_ELEMS + 393216) * sizeof(ushort);
    float* Mpart = (float*)fbase;                          // S_*B*T floats
    float* Lpart = Mpart + (size_t)S_ * B_ * T_;
    ushort* Opart = (ushort*)(Lpart + (size_t)S_ * B_ * T_);  // S_*B*T*H bf16

    prep_w_kernel<<<dim3((E_ * H_ + 255) / 256, 3), 256, 0, stream>>>(Wk, Wq, Wv, Wt);
    proj_kernel<<<dim3((B_ * T_) / 32, 3), 128, 0, stream>>>(k, q, v, Wt, kp, qp, vpt);
    attn_kernel<<<dim3(S_, T_ / 128, B_), 256, 0, stream>>>(kp, qp, vpt, Opart, Mpart, Lpart);
    combine_kernel<<<dim3(B_ * T_ / 2), 256, 0, stream>>>(Opart, Mpart, Lpart, (float*)d_out);
}

// Round 6
// 259.859 us; speedup vs baseline: 1.2478x; 1.0719x over previous
//
#include <hip/hip_runtime.h>
#include <math.h>

#define B_ 4
#define T_ 4096
#define E_ 1024
#define H_ 128
#define S_ 8          // attention split-K factor

typedef __attribute__((ext_vector_type(8))) short short8;
typedef __attribute__((ext_vector_type(4))) float f32x4;
typedef __attribute__((ext_vector_type(16))) float f32x16;
typedef unsigned short ushort;

__device__ __forceinline__ ushort f2bf(float f) {          // RNE
    union { float f; unsigned int u; } v; v.f = f;
    unsigned int r = v.u + 0x7fffu + ((v.u >> 16) & 1u);
    return (ushort)(r >> 16);
}
__device__ __forceinline__ float bf2f(ushort u) {
    union { unsigned int u; float f; } v; v.u = ((unsigned int)u) << 16;
    return v.f;
}
__device__ __forceinline__ unsigned int pkbf(float hi, float lo) { // [bf16(hi)|bf16(lo)] truncated
    return __builtin_amdgcn_perm(__float_as_uint(hi), __float_as_uint(lo), 0x07060302u);
}

typedef __attribute__((address_space(3))) unsigned int lds_u32;
typedef __attribute__((address_space(1))) const unsigned int g_u32;
__device__ __forceinline__ void gload16(const void* g, void* l) {
    __builtin_amdgcn_global_load_lds((g_u32*)g, (lds_u32*)l, 16, 0, 0);
}

// ---------------------------------------------------------------------------
// Kernel 1: W[E][H] fp32 -> Wt[H][E] bf16.  v7: LDS-transpose tile so the
// global write is 16B-granular (was a 2B scatter at 2KB stride).
// Block: tile [16 e][128 h]. Read coalesced fp32 rows; write 16B chunks.
// ---------------------------------------------------------------------------
__global__ void prep_w_kernel(const float* __restrict__ Wk,
                              const float* __restrict__ Wq,
                              const float* __restrict__ Wv,
                              ushort* __restrict__ Wt) {
    int sel = blockIdx.y;
    const float* W = (sel == 0) ? Wk : ((sel == 1) ? Wq : Wv);
    ushort* out = Wt + (size_t)sel * (E_ * H_);

    __shared__ ushort lds[128 * 24];               // [h][e] pad 24 (16B-aligned rows)
    int t = threadIdx.x;
    int e0 = blockIdx.x * 16;

    {   // load [16 e][128 h]: thread -> (eloc = t>>4, hblk = (t&15)*8)
        int eloc = t >> 4, hblk = (t & 15) * 8;
        const float* src = W + (size_t)(e0 + eloc) * H_ + hblk;
        float4 a = *(const float4*)(src);
        float4 b = *(const float4*)(src + 4);
        lds[(hblk + 0) * 24 + eloc] = f2bf(a.x);
        lds[(hblk + 1) * 24 + eloc] = f2bf(a.y);
        lds[(hblk + 2) * 24 + eloc] = f2bf(a.z);
        lds[(hblk + 3) * 24 + eloc] = f2bf(a.w);
        lds[(hblk + 4) * 24 + eloc] = f2bf(b.x);
        lds[(hblk + 5) * 24 + eloc] = f2bf(b.y);
        lds[(hblk + 6) * 24 + eloc] = f2bf(b.z);
        lds[(hblk + 7) * 24 + eloc] = f2bf(b.w);
    }
    __syncthreads();
    {   // write: thread -> (h = t>>1, part = t&1): 8 ushorts = 16B
        int h = t >> 1, part = t & 1;
        *(uint4*)&out[(size_t)h * E_ + e0 + part * 8] =
            *(const uint4*)&lds[h * 24 + part * 8];
    }
}

// ---------------------------------------------------------------------------
// Kernel 2: projection GEMM, M-tile 64 (16 rows/wave), BK=64  [r1 verbatim]
// Prefetch distance 2, 3-deep LDS ring for W, counted vmcnt; best measured.
// ---------------------------------------------------------------------------
__launch_bounds__(256, 3)
__global__ void proj_kernel(const float* __restrict__ Xk,
                            const float* __restrict__ Xq,
                            const float* __restrict__ Xv,
                            const ushort* __restrict__ Wt,
                            ushort* __restrict__ kp,
                            ushort* __restrict__ qp,
                            ushort* __restrict__ vpt) {
    int sel = blockIdx.y;
    const float* X = (sel == 0) ? Xk : ((sel == 1) ? Xq : Xv);
    const ushort* W = Wt + (size_t)sel * (E_ * H_);

    __shared__ __align__(16) ushort smem[24576];   // 48 KB: Ws ring 3 x 8192
    ushort* Ot = smem;                             // epilogue alias [128 h][72]

    int t = threadIdx.x;
    int wave = t >> 6, lane = t & 63;
    int l15 = lane & 15, quad = lane >> 4;
    int m0 = blockIdx.x * 64;
    int koff = (blockIdx.x & 15) * 64;             // per-block k-stagger

    auto stageW = [&](int k0, ushort* buf) {
#pragma unroll
        for (int i = 0; i < 4; i++) {
            int slot = i * 256 + t;
            int row = slot >> 3, jst = slot & 7;
            int jsrc = jst ^ (row & 7);
            gload16(W + (size_t)row * E_ + k0 + jsrc * 8, &buf[slot * 8]);
        }
    };

    const float* xptr = X + (size_t)(m0 + wave * 16 + l15) * E_;
    auto loadX = [&](int k0, float4& a, float4& b, float4& c, float4& d) {
        a = *(const float4*)(xptr + k0 + quad * 8);
        b = *(const float4*)(xptr + k0 + quad * 8 + 4);
        c = *(const float4*)(xptr + k0 + 32 + quad * 8);
        d = *(const float4*)(xptr + k0 + 32 + quad * 8 + 4);
    };

    f32x4 acc[8];
#pragma unroll
    for (int nt = 0; nt < 8; nt++)
#pragma unroll
        for (int j = 0; j < 4; j++) acc[nt][j] = 0.0f;

    // prologue: tiles 0 and 1 both in flight
    float4 x0a, x0b, x0c, x0d, x1a, x1b, x1c, x1d;
    stageW(koff, smem);
    loadX(koff, x0a, x0b, x0c, x0d);
    {
        int k1 = (koff + 64) & (E_ - 1);
        stageW(k1, smem + 8192);
        loadX(k1, x1a, x1b, x1c, x1d);
    }

    auto step = [&](int it, int bc, float4& a, float4& b, float4& c, float4& d) {
        ushort* Wcur = smem + bc * 8192;
        int bn = bc + 2; if (bn >= 3) bn -= 3;     // ring slot for tile it+2
        asm volatile("s_waitcnt lgkmcnt(0)" ::: "memory");
        __builtin_amdgcn_s_barrier();
        union { unsigned int w[4]; short8 s8; } au0, au1;
        au0.w[0] = pkbf(a.y, a.x);  au0.w[1] = pkbf(a.w, a.z);
        au0.w[2] = pkbf(b.y, b.x);  au0.w[3] = pkbf(b.w, b.z);
        au1.w[0] = pkbf(c.y, c.x);  au1.w[1] = pkbf(c.w, c.z);
        au1.w[2] = pkbf(d.y, d.x);  au1.w[3] = pkbf(d.w, d.z);
        if (it < 14) {
            int kn = (koff + (it + 2) * 64) & (E_ - 1);
            stageW(kn, smem + bn * 8192);          // 4 VMEM
            loadX(kn, a, b, c, d);                 // 4 VMEM
            asm volatile("s_waitcnt vmcnt(16)" ::: "memory");
        } else if (it == 14) {
            asm volatile("s_waitcnt vmcnt(8)" ::: "memory");
        } else {
            asm volatile("s_waitcnt vmcnt(0)" ::: "memory");
        }
        __builtin_amdgcn_s_barrier();              // stage(it) visible to all
#pragma unroll
        for (int ks = 0; ks < 2; ks++) {
            const auto& au = ks ? au1 : au0;
#pragma unroll
            for (int nt = 0; nt < 8; nt++) {
                int n = nt * 16 + l15;
                int jj = (ks * 4 + quad) ^ (n & 7);
                short8 bb = *(const short8*)&Wcur[n * 64 + jj * 8];
                acc[nt] = __builtin_amdgcn_mfma_f32_16x16x32_bf16(au.s8, bb, acc[nt], 0, 0, 0);
            }
        }
    };

    int bc = 0;
    for (int ii = 0; ii < 16; ii += 2) {
        step(ii, bc, x0a, x0b, x0c, x0d);
        bc++; if (bc >= 3) bc -= 3;
        step(ii + 1, bc, x1a, x1b, x1c, x1d);
        bc++; if (bc >= 3) bc -= 3;
    }

    if (sel < 2) {
        float scale = (sel == 1) ? 0.08838834764831845f : 1.0f;
        ushort* out = (sel == 0) ? kp : qp;
#pragma unroll
        for (int nt = 0; nt < 8; nt++)
#pragma unroll
            for (int r = 0; r < 4; r++) {
                int row = m0 + wave * 16 + quad * 4 + r;
                out[(size_t)row * H_ + nt * 16 + l15] = f2bf(acc[nt][r] * scale);
            }
    } else {
        __syncthreads();                   // done with Ws before aliasing
#pragma unroll
        for (int nt = 0; nt < 8; nt++) {
            unsigned int p0 = ((unsigned int)f2bf(acc[nt][0])) | ((unsigned int)f2bf(acc[nt][1]) << 16);
            unsigned int p1 = ((unsigned int)f2bf(acc[nt][2])) | ((unsigned int)f2bf(acc[nt][3]) << 16);
            *(uint2*)&Ot[(nt * 16 + l15) * 72 + wave * 16 + quad * 4] = make_uint2(p0, p1);
        }
        __syncthreads();
        int b = m0 >> 12;
        int t0 = m0 & (T_ - 1);
        int h = t >> 1, half = (t & 1) * 32;
        ushort* dst = vpt + (size_t)b * H_ * T_ + (size_t)h * T_ + t0 + half;
        const ushort* src = &Ot[h * 72 + half];
#pragma unroll
        for (int j = 0; j < 4; j++)
            *(uint4*)(dst + j * 8) = *(const uint4*)(src + j * 8);
    }
}

// ---------------------------------------------------------------------------
// Kernel 3: flash attention partials, 32x32x16 MFMA, split-K S_=8 [r1 verbatim]
// ---------------------------------------------------------------------------
__launch_bounds__(256, 2)
__global__ void attn_kernel(const ushort* __restrict__ kp,
                            const ushort* __restrict__ qp,
                            const ushort* __restrict__ vpt,
                            ushort* __restrict__ Opart,
                            float* __restrict__ Mpart,
                            float* __restrict__ Lpart) {
    __shared__ __align__(16) ushort smem[32768];   // 64 KB: 2 x (Ks 8192 + Vs 8192)
    int t = threadIdx.x;
    int wave = t >> 6, lane = t & 63;
    int l31 = lane & 31, h = lane >> 5;
    int s = blockIdx.x;
    int qt = (int)gridDim.y - 1 - (int)blockIdx.y;   // heavy blocks first
    int b = blockIdx.z;
    int q0 = qt * 128;
    int nkt = 2 * qt + 2;
    int query = q0 + wave * 32 + l31;

    const ushort* kbase = kp + (size_t)b * T_ * H_;
    const ushort* vbase = vpt + (size_t)b * H_ * T_;

    // Q as B-operand (32x32x16): B[n=query=lane&31][k=h=(lane>>5)*8+j], 8 steps
    short8 qf[8];
#pragma unroll
    for (int kh = 0; kh < 8; kh++)
        qf[kh] = *(const short8*)(qp + ((size_t)b * T_ + query) * H_ + kh * 16 + h * 8);

    f32x16 ao[4];                         // O^T acc: [hc][reg], col = query
#pragma unroll
    for (int hc = 0; hc < 4; hc++)
#pragma unroll
        for (int j = 0; j < 16; j++) ao[hc][j] = 0.0f;
    float m_i = -INFINITY, l_i = 0.0f;

    auto stage = [&](int kt, int buf) {
        ushort* Ksb = smem + buf * 16384;
        ushort* Vsb = Ksb + 8192;
        int k0 = kt * 64;
#pragma unroll
        for (int i = 0; i < 4; i++) {
            int slot = i * 256 + t;
            int row = slot >> 4, jst = slot & 15;
            int jsrc = jst ^ (row & 15);
            gload16(kbase + (size_t)(k0 + row) * H_ + jsrc * 8, &Ksb[slot * 8]);
        }
#pragma unroll
        for (int i = 0; i < 4; i++) {
            int slot = i * 256 + t;
            int row = slot >> 3, jst = slot & 7;
            int jsrc = jst ^ (row & 7);
            gload16(vbase + (size_t)row * T_ + k0 + jsrc * 8, &Vsb[slot * 8]);
        }
    };

    int cur = 0;
    if (s < nkt) stage(s, 0);

    for (int kt = s; kt < nkt; kt += S_) {
        __syncthreads();                   // cur buffers ready
        if (kt + S_ < nkt) stage(kt + S_, cur ^ 1);
        const ushort* Ksb = smem + cur * 16384;
        const ushort* Vsb = Ksb + 8192;
        int k0 = kt * 64;

        // S^T = K Q^T : s0 = keys 0..31, s1 = keys 32..63; col = query
        f32x16 s0, s1;
#pragma unroll
        for (int j = 0; j < 16; j++) { s0[j] = 0.0f; s1[j] = 0.0f; }
#pragma unroll
        for (int kh = 0; kh < 8; kh++) {
            int slot = (kh * 2 + h) ^ (l31 & 15);
            short8 a0 = *(const short8*)&Ksb[l31 * 128 + slot * 8];
            short8 a1 = *(const short8*)&Ksb[(32 + l31) * 128 + slot * 8];
            s0 = __builtin_amdgcn_mfma_f32_32x32x16_bf16(a0, qf[kh], s0, 0, 0, 0);
            s1 = __builtin_amdgcn_mfma_f32_32x32x16_bf16(a1, qf[kh], s1, 0, 0, 0);
        }

        // causal mask: key row = (r&3)+8*(r>>2)+4h (+32 for s1)
        if (k0 + 63 > q0 + wave * 32) {
#pragma unroll
            for (int rq = 0; rq < 4; rq++)
#pragma unroll
                for (int rr = 0; rr < 4; rr++) {
                    int koff = rr + rq * 8 + h * 4;
                    if (k0 + koff > query)      s0[rq * 4 + rr] = -INFINITY;
                    if (k0 + 32 + koff > query) s1[rq * 4 + rr] = -INFINITY;
                }
        }

        // online softmax per query (in-lane over 32 + one shfl_xor(32))
        float cmax = -INFINITY;
#pragma unroll
        for (int j = 0; j < 16; j++) cmax = fmaxf(cmax, fmaxf(s0[j], s1[j]));
        cmax = fmaxf(cmax, __shfl_xor(cmax, 32));
        float mnew = fmaxf(m_i, cmax);
        float msafe = fmaxf(mnew, -1e30f);
        float alpha = __expf(m_i - msafe);
        m_i = mnew;
        float rs = 0.0f;
#pragma unroll
        for (int j = 0; j < 16; j++) {
            s0[j] = __expf(s0[j] - msafe);
            s1[j] = __expf(s1[j] - msafe);
            rs += s0[j] + s1[j];
        }
        rs += __shfl_xor(rs, 32);
        l_i = l_i * alpha + rs;
#pragma unroll
        for (int hc = 0; hc < 4; hc++)
#pragma unroll
            for (int j = 0; j < 16; j++) ao[hc][j] *= alpha;

        // O^T += V^T P^T ; P^T B-frag built via shfl_xor(32) from S^T C-frags
#pragma unroll
        for (int kk = 0; kk < 4; kk++) {
            const f32x16& sf = (kk < 2) ? s0 : s1;
            int base = (kk & 1) * 8;
            unsigned int q0x = pkbf(sf[base + 1], sf[base + 0]);
            unsigned int q0y = pkbf(sf[base + 3], sf[base + 2]);
            unsigned int q1x = pkbf(sf[base + 5], sf[base + 4]);
            unsigned int q1y = pkbf(sf[base + 7], sf[base + 6]);
            unsigned int t0x = __shfl_xor(q0x, 32);
            unsigned int t0y = __shfl_xor(q0y, 32);
            unsigned int t1x = __shfl_xor(q1x, 32);
            unsigned int t1y = __shfl_xor(q1y, 32);
            union { unsigned int w[4]; short8 s8; } bu;
            bu.w[0] = h ? t1x : q0x;
            bu.w[1] = h ? t1y : q0y;
            bu.w[2] = h ? q1x : t0x;
            bu.w[3] = h ? q1y : t0y;
#pragma unroll
            for (int hc = 0; hc < 4; hc++) {
                int row = hc * 32 + l31;
                int slot = (kk * 2 + h) ^ (row & 7);
                short8 av = *(const short8*)&Vsb[row * 64 + slot * 8];
                ao[hc] = __builtin_amdgcn_mfma_f32_32x32x16_bf16(av, bu.s8, ao[hc], 0, 0, 0);
            }
        }
        cur ^= 1;
    }

    // epilogue
    const size_t BT = (size_t)B_ * T_;
    __syncthreads();                       // all compute done before aliasing smem
    if (lane < 32) {
        int grow = b * T_ + query;
        Mpart[(size_t)s * BT + grow] = m_i;
        Lpart[(size_t)s * BT + grow] = l_i;
    }
    ushort* Ot = smem;                     // [128 q][136]
#pragma unroll
    for (int hc = 0; hc < 4; hc++)
#pragma unroll
        for (int rq = 0; rq < 4; rq++) {
            uint2 w = make_uint2(
                ((unsigned int)f2bf(ao[hc][rq * 4 + 0])) | ((unsigned int)f2bf(ao[hc][rq * 4 + 1]) << 16),
                ((unsigned int)f2bf(ao[hc][rq * 4 + 2])) | ((unsigned int)f2bf(ao[hc][rq * 4 + 3]) << 16));
            *(uint2*)&Ot[(wave * 32 + l31) * 136 + hc * 32 + rq * 8 + h * 4] = w;
        }
    __syncthreads();
    {
        int qq = t >> 1, half = (t & 1) * 64;
        size_t row = (size_t)s * BT + b * T_ + q0 + qq;
        ushort* dst = Opart + row * H_ + half;
        const ushort* src = &Ot[qq * 136 + half];
#pragma unroll
        for (int j = 0; j < 8; j++)
            *(uint4*)(dst + j * 8) = *(const uint4*)(src + j * 8);
    }
}

// ---------------------------------------------------------------------------
// Kernel 4: combine split-K partials.  v7: uint (2-col) Opart reads = 4B/lane
// coalesced (was 2B/lane scalar), float2 writes = 8B/lane.
// Block: 4 rows x 64 col-pairs.
// ---------------------------------------------------------------------------
__launch_bounds__(256)
__global__ void combine_kernel(const ushort* __restrict__ Opart,
                               const float* __restrict__ Mpart,
                               const float* __restrict__ Lpart,
                               float* __restrict__ out) {
    int t = threadIdx.x;
    int row = blockIdx.x * 4 + (t >> 6);
    int col = (t & 63) * 2;
    const size_t BT = (size_t)B_ * T_;
    float m[S_], l[S_];
#pragma unroll
    for (int s = 0; s < S_; s++) {
        m[s] = Mpart[(size_t)s * BT + row];
        l[s] = Lpart[(size_t)s * BT + row];
    }
    float M = m[0];
#pragma unroll
    for (int s = 1; s < S_; s++) M = fmaxf(M, m[s]);
    float den = 0.0f, a0 = 0.0f, a1 = 0.0f;
#pragma unroll
    for (int s = 0; s < S_; s++) {
        float w = __expf(m[s] - M);
        den += l[s] * w;
        unsigned int u = *(const unsigned int*)&Opart[((size_t)s * BT + row) * H_ + col];
        a0 += w * bf2f((ushort)(u & 0xffffu));
        a1 += w * bf2f((ushort)(u >> 16));
    }
    float inv = 1.0f / den;
    *(float2*)&out[(size_t)row * H_ + col] = make_float2(a0 * inv, a1 * inv);
}

// ---------------------------------------------------------------------------
extern "C" void kernel_launch(void* const* d_in, const int* in_sizes, int n_in,
                              void* d_out, int out_size, void* d_ws, size_t ws_size,
                              hipStream_t stream) {
    (void)in_sizes; (void)n_in; (void)out_size; (void)ws_size;
    const float* k  = (const float*)d_in[0];
    const float* q  = (const float*)d_in[1];
    const float* v  = (const float*)d_in[2];
    const float* Wk = (const float*)d_in[3];
    const float* Wq = (const float*)d_in[4];
    const float* Wv = (const float*)d_in[5];

    ushort* wsu = (ushort*)d_ws;
    const size_t PROJ_ELEMS = (size_t)B_ * T_ * H_;        // 2,097,152
    ushort* kp  = wsu;
    ushort* qp  = wsu + PROJ_ELEMS;
    ushort* vpt = wsu + 2 * PROJ_ELEMS;
    ushort* Wt  = wsu + 3 * PROJ_ELEMS;                    // 393,216 ushorts
    char*  fbase = (char*)d_ws + (3 * PROJ_ELEMS + 393216) * sizeof(ushort);
    float* Mpart = (float*)fbase;                          // S_*B*T floats
    float* Lpart = Mpart + (size_t)S_ * B_ * T_;
    ushort* Opart = (ushort*)(Lpart + (size_t)S_ * B_ * T_);  // S_*B*T*H bf16

    prep_w_kernel<<<dim3(E_ / 16, 3), 256, 0, stream>>>(Wk, Wq, Wv, Wt);
    proj_kernel<<<dim3((B_ * T_) / 64, 3), 256, 0, stream>>>(k, q, v, Wt, kp, qp, vpt);
    attn_kernel<<<dim3(S_, T_ / 128, B_), 256, 0, stream>>>(kp, qp, vpt, Opart, Mpart, Lpart);
    combine_kernel<<<dim3(B_ * T_ / 4), 256, 0, stream>>>(Opart, Mpart, Lpart, (float*)d_out);
}